// Round 2
// baseline (136.684 us; speedup 1.0000x reference)
//
#include <hip/hip_runtime.h>
#include <hip/hip_bf16.h>
#include <math.h>

#define B_ 8
#define L_ 256
#define E_ 256
#define H_ 8
#define A_ 32

// ---------------------------------------------------------------------------
// NT GEMM: C[M,N] = A[M,K] * B[N,K]^T   (both row-major along K)
// MODE 0: plain write to C0[M*N]
// MODE 1: scatter qk -> q (C0) / k (C1) in (b,h,l,a) layout
// ---------------------------------------------------------------------------
template <int MODE>
__global__ __launch_bounds__(256) void gemm_nt(const float* __restrict__ A,
                                               const float* __restrict__ Bm,
                                               float* __restrict__ C0,
                                               float* __restrict__ C1, int M,
                                               int N, int K) {
  __shared__ float As[64][65];
  __shared__ float Bs[64][65];
  const int ntile = N >> 6;
  const int mt = blockIdx.x / ntile;
  const int nt = blockIdx.x % ntile;
  const int t = threadIdx.x;
  const int tx = t & 15;   // 16 cols of threads -> 4 output cols each
  const int ty = t >> 4;   // 16 rows of threads -> 4 output rows each

  float acc[4][4] = {};

  for (int kt = 0; kt < K; kt += 64) {
#pragma unroll
    for (int r = 0; r < 16; ++r) {
      int idx = r * 256 + t;        // 0..4095
      int row = idx >> 6, col = idx & 63;
      As[row][col] = A[(mt * 64 + row) * K + kt + col];
      Bs[row][col] = Bm[(nt * 64 + row) * K + kt + col];
    }
    __syncthreads();
#pragma unroll
    for (int kk = 0; kk < 64; ++kk) {
      float a[4], b[4];
#pragma unroll
      for (int r = 0; r < 4; ++r) a[r] = As[ty * 4 + r][kk];
#pragma unroll
      for (int c = 0; c < 4; ++c) b[c] = Bs[tx * 4 + c][kk];
#pragma unroll
      for (int r = 0; r < 4; ++r)
#pragma unroll
        for (int c = 0; c < 4; ++c) acc[r][c] += a[r] * b[c];
    }
    __syncthreads();
  }

#pragma unroll
  for (int r = 0; r < 4; ++r) {
#pragma unroll
    for (int c = 0; c < 4; ++c) {
      int gr = mt * 64 + ty * 4 + r;  // global row (b*L + l)
      int go = nt * 64 + tx * 4 + c;  // global col
      if (MODE == 0) {
        C0[gr * N + go] = acc[r][c];
      } else {
        int b = gr >> 8, l = gr & 255;
        int h = go >> 6, x = go & 63;
        if (x < A_)
          C0[((b * H_ + h) * L_ + l) * A_ + x] = acc[r][c];
        else
          C1[((b * H_ + h) * L_ + l) * A_ + (x - A_)] = acc[r][c];
      }
    }
  }
}

// ---------------------------------------------------------------------------
// Attention kernel: one block handles (b,h) x 32-row i-tile.
// scores[i,j] = sum_a w_a * leaky(k[i,a] + q[j,a])   <-- row side is K!
// attn = softmax_j(mask(scores));  vals[i,a] = sum_j attn[i,j] * k[j,a]
// 4 waves; wave w owns rows ii = w, w+4, ... (8 rows each).
// Per row: 64 lanes cover j in {c*64+lane}, c=0..3.
// ---------------------------------------------------------------------------
#define ITILE 32

__global__ __launch_bounds__(256, 2) void attn_kernel(
    const float* __restrict__ q, const float* __restrict__ k,
    const int* __restrict__ adj, const float* __restrict__ w_attn,
    float* __restrict__ vals) {
  __shared__ float Qc[L_][A_ + 1];   // q[b,h,j,:]  (score column operand)
  __shared__ float Kc[L_][A_ + 1];   // k[b,h,j,:]  (PV operand)
  __shared__ float Kr[ITILE][A_];    // k[b,h,i,:]  (score row operand)
  __shared__ float wl[A_];
  __shared__ float attn_row[4][L_];

  const int bh = blockIdx.x >> 3;   // L_/ITILE = 8 i-tiles
  const int it = blockIdx.x & 7;
  const int b = bh >> 3, h = bh & 7;
  const int t = threadIdx.x;

  const float* qbase = q + bh * (L_ * A_);
  const float* kbase = k + bh * (L_ * A_);
#pragma unroll
  for (int r = 0; r < 32; ++r) {
    int idx = r * 256 + t;          // 0..8191
    Qc[idx >> 5][idx & 31] = qbase[idx];
    Kc[idx >> 5][idx & 31] = kbase[idx];
  }
  const float* krow = kbase + it * ITILE * A_;
#pragma unroll
  for (int r = 0; r < 4; ++r) {
    int idx = r * 256 + t;
    Kr[idx >> 5][idx & 31] = krow[idx];
  }
  if (t < A_) wl[t] = w_attn[t];
  __syncthreads();

  const int wave = t >> 6, lane = t & 63;
  const int* adjb = adj + b * (L_ * L_);

  // every wave runs exactly ITILE/4 = 8 iterations -> barriers are uniform
  for (int ii = wave; ii < ITILE; ii += 4) {
    const int i = it * ITILE + ii;
    float p[4];
#pragma unroll
    for (int c = 0; c < 4; ++c) p[c] = 0.f;
#pragma unroll
    for (int a = 0; a < A_; ++a) {
      float ra = Kr[ii][a];         // k[i,a]
      float wa = wl[a];
#pragma unroll
      for (int c = 0; c < 4; ++c) {
        float x = ra + Qc[c * 64 + lane][a];   // + q[j,a]
        x = fmaxf(x, 0.2f * x);     // leaky relu
        p[c] += wa * x;
      }
    }
    float m = -1e30f;
#pragma unroll
    for (int c = 0; c < 4; ++c) {
      int j = c * 64 + lane;
      if (adjb[i * L_ + j] == 0) p[c] = -1e30f;
      m = fmaxf(m, p[c]);
    }
#pragma unroll
    for (int off = 32; off >= 1; off >>= 1) m = fmaxf(m, __shfl_xor(m, off));
    float sum = 0.f;
#pragma unroll
    for (int c = 0; c < 4; ++c) {
      p[c] = __expf(p[c] - m);      // masked -> exp(-huge) = 0
      sum += p[c];
    }
#pragma unroll
    for (int off = 32; off >= 1; off >>= 1) sum += __shfl_xor(sum, off);
    float inv = 1.f / sum;
#pragma unroll
    for (int c = 0; c < 4; ++c) attn_row[wave][c * 64 + lane] = p[c] * inv;
    __syncthreads();
    // PV: lanes split (a, j-half); attn row read from this wave's LDS slice
    const int a = lane & 31, cc = lane >> 5;
    float partial = 0.f;
#pragma unroll 8
    for (int j = cc * 128; j < cc * 128 + 128; ++j)
      partial += attn_row[wave][j] * Kc[j][a];
    partial += __shfl_down(partial, 32);
    if (lane < 32) vals[(b * L_ + i) * E_ + h * A_ + a] = partial;
    __syncthreads();
  }
}

extern "C" void kernel_launch(void* const* d_in, const int* in_sizes, int n_in,
                              void* d_out, int out_size, void* d_ws,
                              size_t ws_size, hipStream_t stream) {
  const float* emb = (const float*)d_in[0];
  const int* adj = (const int*)d_in[1];
  const float* W_qk = (const float*)d_in[2];
  const float* w_attn = (const float*)d_in[3];
  const float* W_out = (const float*)d_in[4];
  float* out = (float*)d_out;

  float* q = (float*)d_ws;                    // B*H*L*A = 524288 floats
  float* k = q + B_ * H_ * L_ * A_;           // 524288 floats
  float* vals = k + B_ * H_ * L_ * A_;        // B*L*E = 524288 floats

  // qk = emb @ W_qk^T, scattered into q/k (b,h,l,a)
  gemm_nt<1><<<dim3((2048 / 64) * (512 / 64)), 256, 0, stream>>>(
      emb, W_qk, q, k, 2048, 512, 256);
  // attention
  attn_kernel<<<dim3(B_ * H_ * (L_ / ITILE)), 256, 0, stream>>>(q, k, adj,
                                                                w_attn, vals);
  // out = vals @ W_out^T
  gemm_nt<0><<<dim3((2048 / 64) * (256 / 64)), 256, 0, stream>>>(
      vals, W_out, out, nullptr, 2048, 256, 256);
}

// Round 4
// 125.688 us; speedup vs baseline: 1.0875x; 1.0875x over previous
//
#include <hip/hip_runtime.h>
#include <hip/hip_bf16.h>
#include <math.h>

#define B_ 8
#define L_ 256
#define E_ 256
#define H_ 8
#define A_ 32
#define ITILE 32

typedef __attribute__((ext_vector_type(8))) short bf16x8;
typedef __attribute__((ext_vector_type(4))) float f32x4;

// ---------------------------------------------------------------------------
// NT GEMM: C[M,N] = A[M,K] * B[N,K]^T, fp32 VALU, transposed-LDS b128 reads.
// MODE 0: plain write to C0[M*N]
// MODE 1: scatter qk -> q (C0) / k (C1) in (b,h,l,a) layout
// ---------------------------------------------------------------------------
template <int MODE>
__global__ __launch_bounds__(256) void gemm_nt(const float* __restrict__ A,
                                               const float* __restrict__ Bm,
                                               float* __restrict__ C0,
                                               float* __restrict__ C1, int M,
                                               int N, int K) {
  // transposed: As[kk][row], row-stride 68 floats = 272B (16B-aligned rows)
  __shared__ __align__(16) float As[64][68];
  __shared__ __align__(16) float Bs[64][68];
  const int ntile = N >> 6;
  const int mt = blockIdx.x / ntile;
  const int nt = blockIdx.x % ntile;
  const int t = threadIdx.x;
  const int tx = t & 15;
  const int ty = t >> 4;

  float acc[4][4] = {};

  for (int kt = 0; kt < K; kt += 64) {
#pragma unroll
    for (int r = 0; r < 4; ++r) {
      int idx4 = r * 256 + t;        // 0..1023 -> 64 rows x 16 k-quads
      int row = idx4 >> 4;
      int kq = idx4 & 15;
      float4 av =
          *(const float4*)&A[(mt * 64 + row) * K + kt + kq * 4];
      As[kq * 4 + 0][row] = av.x;
      As[kq * 4 + 1][row] = av.y;
      As[kq * 4 + 2][row] = av.z;
      As[kq * 4 + 3][row] = av.w;
      float4 bv =
          *(const float4*)&Bm[(nt * 64 + row) * K + kt + kq * 4];
      Bs[kq * 4 + 0][row] = bv.x;
      Bs[kq * 4 + 1][row] = bv.y;
      Bs[kq * 4 + 2][row] = bv.z;
      Bs[kq * 4 + 3][row] = bv.w;
    }
    __syncthreads();
#pragma unroll 16
    for (int kk = 0; kk < 64; ++kk) {
      float4 a4 = *(const float4*)&As[kk][ty * 4];
      float4 b4 = *(const float4*)&Bs[kk][tx * 4];
      float ar[4] = {a4.x, a4.y, a4.z, a4.w};
      float br[4] = {b4.x, b4.y, b4.z, b4.w};
#pragma unroll
      for (int r = 0; r < 4; ++r)
#pragma unroll
        for (int c = 0; c < 4; ++c) acc[r][c] = fmaf(ar[r], br[c], acc[r][c]);
    }
    __syncthreads();
  }

#pragma unroll
  for (int r = 0; r < 4; ++r) {
#pragma unroll
    for (int c = 0; c < 4; ++c) {
      int gr = mt * 64 + ty * 4 + r;
      int go = nt * 64 + tx * 4 + c;
      if (MODE == 0) {
        C0[gr * N + go] = acc[r][c];
      } else {
        int b = gr >> 8, l = gr & 255;
        int h = go >> 6, x = go & 63;
        if (x < A_)
          C0[((b * H_ + h) * L_ + l) * A_ + x] = acc[r][c];
        else
          C1[((b * H_ + h) * L_ + l) * A_ + (x - A_)] = acc[r][c];
      }
    }
  }
}

// ---------------------------------------------------------------------------
// Attention: block = (b,h, 32-row i-tile), 4 waves, wave w owns rows w*8..w*8+7.
// scores[i,j] = sum_a w_a*leaky(k[i,a]+q[j,a])
//             = 0.6*(ck[i]+cq[j]) + 0.4*sum_a w_a*|k[i,a]+q[j,a]|
// softmax over j (adj-masked), then PV (probs @ K) via bf16 MFMA 16x16x32.
// ---------------------------------------------------------------------------
__global__ __launch_bounds__(256, 2) void attn_kernel(
    const float* __restrict__ q, const float* __restrict__ k,
    const int* __restrict__ adj, const float* __restrict__ w_attn,
    float* __restrict__ vals) {
  __shared__ __align__(16) float Qt[A_][260];            // q^T: Qt[a][j] fp32
  __shared__ __align__(16) __hip_bfloat16 KT[A_][264];   // k^T: KT[a][j] bf16
  __shared__ __align__(16) float Kr[ITILE][36];          // k rows (i) fp32
  __shared__ __align__(16) __hip_bfloat16 S[ITILE][264]; // probs bf16
  __shared__ __align__(16) float wsh[A_];

  const int bh = blockIdx.x >> 3;
  const int it = blockIdx.x & 7;
  const int b = bh >> 3, h = bh & 7;
  const int t = threadIdx.x;

  // ---- stage ----
  const float4* qb4 = (const float4*)(q + bh * (L_ * A_));
  const float4* kb4 = (const float4*)(k + bh * (L_ * A_));
#pragma unroll
  for (int r = 0; r < 8; ++r) {
    int idx4 = r * 256 + t;         // 0..2047 ; j = idx4>>3, ab = idx4&7
    int j = idx4 >> 3, ab = idx4 & 7;
    float4 v = qb4[idx4];
    Qt[ab * 4 + 0][j] = v.x;
    Qt[ab * 4 + 1][j] = v.y;
    Qt[ab * 4 + 2][j] = v.z;
    Qt[ab * 4 + 3][j] = v.w;
    float4 u = kb4[idx4];
    KT[ab * 4 + 0][j] = __float2bfloat16(u.x);
    KT[ab * 4 + 1][j] = __float2bfloat16(u.y);
    KT[ab * 4 + 2][j] = __float2bfloat16(u.z);
    KT[ab * 4 + 3][j] = __float2bfloat16(u.w);
  }
  {
    const float4* kr4g = (const float4*)(k + bh * (L_ * A_) + it * ITILE * A_);
    int ii = t >> 3, ab = t & 7;    // 256 threads cover 32 rows x 8 quads
    float4 v = kr4g[t];
    Kr[ii][ab * 4 + 0] = v.x;
    Kr[ii][ab * 4 + 1] = v.y;
    Kr[ii][ab * 4 + 2] = v.z;
    Kr[ii][ab * 4 + 3] = v.w;
  }
  if (t < A_) wsh[t] = w_attn[t];
  __syncthreads();

  const int wave = t >> 6, lane = t & 63;
  const int w8 = wave * 8;
  const int i0 = it * ITILE + w8;
  const int* adjb = adj + b * (L_ * L_);

  // prefetch adjacency for this wave's 8 rows (compile-time indexed)
  int adjv[8][4];
#pragma unroll
  for (int r = 0; r < 8; ++r)
#pragma unroll
    for (int c = 0; c < 4; ++c)
      adjv[r][c] = adjb[(i0 + r) * L_ + c * 64 + lane];

  // ---- scores ----
  float p[8][4] = {};   // sum_a w_a*|k+q|
  float ck[8] = {};
  float cq[4] = {};
#pragma unroll 2
  for (int ab = 0; ab < 8; ++ab) {
    float4 wv = *(const float4*)&wsh[ab * 4];
    float4 kr4[8];
#pragma unroll
    for (int r = 0; r < 8; ++r)
      kr4[r] = *(const float4*)&Kr[w8 + r][ab * 4];
#pragma unroll
    for (int r = 0; r < 8; ++r) {
      ck[r] = fmaf(wv.x, kr4[r].x, ck[r]);
      ck[r] = fmaf(wv.y, kr4[r].y, ck[r]);
      ck[r] = fmaf(wv.z, kr4[r].z, ck[r]);
      ck[r] = fmaf(wv.w, kr4[r].w, ck[r]);
    }
#pragma unroll
    for (int c = 0; c < 4; ++c) {
      const int j = c * 64 + lane;
      float q0 = Qt[ab * 4 + 0][j];
      float q1 = Qt[ab * 4 + 1][j];
      float q2 = Qt[ab * 4 + 2][j];
      float q3 = Qt[ab * 4 + 3][j];
      cq[c] = fmaf(wv.x, q0, cq[c]);
      cq[c] = fmaf(wv.y, q1, cq[c]);
      cq[c] = fmaf(wv.z, q2, cq[c]);
      cq[c] = fmaf(wv.w, q3, cq[c]);
#pragma unroll
      for (int r = 0; r < 8; ++r) {
        p[r][c] = fmaf(wv.x, fabsf(kr4[r].x + q0), p[r][c]);
        p[r][c] = fmaf(wv.y, fabsf(kr4[r].y + q1), p[r][c]);
        p[r][c] = fmaf(wv.z, fabsf(kr4[r].z + q2), p[r][c]);
        p[r][c] = fmaf(wv.w, fabsf(kr4[r].w + q3), p[r][c]);
      }
    }
  }

  // ---- masked softmax per row, write bf16 probs ----
#pragma unroll
  for (int r = 0; r < 8; ++r) {
    float s[4];
    float m = -3.0e38f;
#pragma unroll
    for (int c = 0; c < 4; ++c) {
      float sc = fmaf(0.4f, p[r][c], 0.6f * (ck[r] + cq[c]));
      s[c] = adjv[r][c] ? sc : -3.0e38f;
      m = fmaxf(m, s[c]);
    }
#pragma unroll
    for (int off = 32; off >= 1; off >>= 1) m = fmaxf(m, __shfl_xor(m, off));
    float sum = 0.f;
#pragma unroll
    for (int c = 0; c < 4; ++c) {
      s[c] = __expf(s[c] - m);
      sum += s[c];
    }
#pragma unroll
    for (int off = 32; off >= 1; off >>= 1) sum += __shfl_xor(sum, off);
    float inv = 1.0f / sum;
#pragma unroll
    for (int c = 0; c < 4; ++c)
      S[w8 + r][c * 64 + lane] = __float2bfloat16(s[c] * inv);
  }
  __syncthreads();

  // ---- PV via MFMA: (32i x 256j) @ (256j x 32a), wave owns 16x16 quadrant --
  const int mi = wave >> 1;          // i-quadrant
  const int ai = wave & 1;           // a-quadrant
  const int fr = lane & 15;
  const int fk = (lane >> 4) * 8;
  f32x4 acc = {0.f, 0.f, 0.f, 0.f};
#pragma unroll
  for (int kt = 0; kt < 8; ++kt) {
    bf16x8 afrag = *(const bf16x8*)&S[mi * 16 + fr][kt * 32 + fk];
    bf16x8 bfrag = *(const bf16x8*)&KT[ai * 16 + fr][kt * 32 + fk];
    acc = __builtin_amdgcn_mfma_f32_16x16x32_bf16(afrag, bfrag, acc, 0, 0, 0);
  }
  const int arow = ai * 16 + fr;                 // a index (C col)
  const int rbase = mi * 16 + ((lane >> 4) << 2);
#pragma unroll
  for (int g = 0; g < 4; ++g) {
    int i = it * ITILE + rbase + g;
    vals[(b * L_ + i) * E_ + h * A_ + arow] = acc[g];
  }
}

extern "C" void kernel_launch(void* const* d_in, const int* in_sizes, int n_in,
                              void* d_out, int out_size, void* d_ws,
                              size_t ws_size, hipStream_t stream) {
  const float* emb = (const float*)d_in[0];
  const int* adj = (const int*)d_in[1];
  const float* W_qk = (const float*)d_in[2];
  const float* w_attn = (const float*)d_in[3];
  const float* W_out = (const float*)d_in[4];
  float* out = (float*)d_out;

  float* q = (float*)d_ws;
  float* k = q + B_ * H_ * L_ * A_;
  float* vals = k + B_ * H_ * L_ * A_;

  gemm_nt<1><<<dim3((2048 / 64) * (512 / 64)), 256, 0, stream>>>(
      emb, W_qk, q, k, 2048, 512, 256);
  attn_kernel<<<dim3(B_ * H_ * (L_ / ITILE)), 256, 0, stream>>>(q, k, adj,
                                                                w_attn, vals);
  gemm_nt<0><<<dim3((2048 / 64) * (256 / 64)), 256, 0, stream>>>(
      vals, W_out, out, nullptr, 2048, 256, 256);
}

// Round 5
// 98.744 us; speedup vs baseline: 1.3842x; 1.2729x over previous
//
#include <hip/hip_runtime.h>
#include <hip/hip_bf16.h>
#include <math.h>

#define B_ 8
#define L_ 256
#define E_ 256
#define H_ 8
#define A_ 32
#define ITILE 32

typedef __attribute__((ext_vector_type(8))) short bf16x8;
typedef __attribute__((ext_vector_type(4))) float f32x4;

// ---------------------------------------------------------------------------
// Swizzled byte offset inside a [64 rows][64 bf16] LDS tile (128 B rows).
// XOR of the 16B-slot index with (row&7) spreads the 16-rows-same-slot
// ds_read_b128 frag fetch across all 32 banks (else 16-way conflict).
// ---------------------------------------------------------------------------
__device__ __forceinline__ int swz(int row, int slot) {
  return row * 128 + ((slot ^ (row & 7)) << 4);
}

__device__ __forceinline__ void pack8(const float4& x, const float4& y,
                                      bf16x8& h, bf16x8& l) {
  float v[8] = {x.x, x.y, x.z, x.w, y.x, y.y, y.z, y.w};
  union { __hip_bfloat16 b[8]; bf16x8 v; } uh, ul;
#pragma unroll
  for (int i = 0; i < 8; ++i) {
    uh.b[i] = __float2bfloat16(v[i]);
    ul.b[i] = __float2bfloat16(v[i] - __bfloat162float(uh.b[i]));
  }
  h = uh.v;
  l = ul.v;
}

// ---------------------------------------------------------------------------
// NT GEMM via bf16 MFMA with hi/lo compensation (fp32-grade accuracy):
//   C = Ah*Bh + Ah*Bl + Al*Bh   (error ~2^-18 relative)
// C[M,N] = A[M,K=256] * B[N,K=256]^T.
// MODE 0: C0[M*N].  MODE 1: scatter to q (C0) / k (C1) in (b,h,l,a).
// Block: 256 thr / 4 waves; tile 64x64; wave quadrant 32x32 = 2x2 frags.
// ---------------------------------------------------------------------------
template <int MODE>
__global__ __launch_bounds__(256) void gemm_mfma(const float* __restrict__ Ag,
                                                 const float* __restrict__ Bg,
                                                 float* __restrict__ C0,
                                                 float* __restrict__ C1,
                                                 int N) {
  __shared__ __align__(16) char lds[4 * 8192];  // Ah | Al | Bh | Bl
  char* Ah = lds;
  char* Al = lds + 8192;
  char* Bh = lds + 16384;
  char* Bl = lds + 24576;

  const int ntile = N >> 6;
  const int mt = blockIdx.x / ntile;
  const int nt = blockIdx.x % ntile;
  const int t = threadIdx.x;
  const int wave = t >> 6, lane = t & 63;
  const int wr = wave >> 1, wc = wave & 1;
  const int r15 = lane & 15, g4 = lane >> 4;
  const int srow = t >> 2, sq = t & 3;  // staging: row 0..63, 16-col quad

  f32x4 acc[2][2];
#pragma unroll
  for (int rb = 0; rb < 2; ++rb)
#pragma unroll
    for (int cb = 0; cb < 2; ++cb) acc[rb][cb] = (f32x4){0.f, 0.f, 0.f, 0.f};

  for (int kt = 0; kt < 256; kt += 64) {
    // ---- stage A,B chunk as hi/lo bf16 (reg-staged, swizzled writes) ----
    const float4* ap4 =
        (const float4*)(Ag + (mt * 64 + srow) * 256 + kt + sq * 16);
    const float4* bp4 =
        (const float4*)(Bg + (nt * 64 + srow) * 256 + kt + sq * 16);
    float4 a0 = ap4[0], a1 = ap4[1], a2 = ap4[2], a3 = ap4[3];
    float4 b0 = bp4[0], b1 = bp4[1], b2 = bp4[2], b3 = bp4[3];
    bf16x8 h, l;
    pack8(a0, a1, h, l);
    *(bf16x8*)(Ah + swz(srow, 2 * sq)) = h;
    *(bf16x8*)(Al + swz(srow, 2 * sq)) = l;
    pack8(a2, a3, h, l);
    *(bf16x8*)(Ah + swz(srow, 2 * sq + 1)) = h;
    *(bf16x8*)(Al + swz(srow, 2 * sq + 1)) = l;
    pack8(b0, b1, h, l);
    *(bf16x8*)(Bh + swz(srow, 2 * sq)) = h;
    *(bf16x8*)(Bl + swz(srow, 2 * sq)) = l;
    pack8(b2, b3, h, l);
    *(bf16x8*)(Bh + swz(srow, 2 * sq + 1)) = h;
    *(bf16x8*)(Bl + swz(srow, 2 * sq + 1)) = l;
    __syncthreads();

    // ---- frag loads + MFMA ----
    bf16x8 fah[2][2], fal[2][2], fbh[2][2], fbl[2][2];  // [blk][kslab]
#pragma unroll
    for (int rb = 0; rb < 2; ++rb)
#pragma unroll
      for (int ks = 0; ks < 2; ++ks) {
        int slot = 4 * ks + g4;
        int arow = wr * 32 + rb * 16 + r15;
        fah[rb][ks] = *(const bf16x8*)(Ah + swz(arow, slot));
        fal[rb][ks] = *(const bf16x8*)(Al + swz(arow, slot));
        int brow = wc * 32 + rb * 16 + r15;
        fbh[rb][ks] = *(const bf16x8*)(Bh + swz(brow, slot));
        fbl[rb][ks] = *(const bf16x8*)(Bl + swz(brow, slot));
      }
#pragma unroll
    for (int rb = 0; rb < 2; ++rb)
#pragma unroll
      for (int cb = 0; cb < 2; ++cb)
#pragma unroll
        for (int ks = 0; ks < 2; ++ks) {
          acc[rb][cb] = __builtin_amdgcn_mfma_f32_16x16x32_bf16(
              fal[rb][ks], fbh[cb][ks], acc[rb][cb], 0, 0, 0);
          acc[rb][cb] = __builtin_amdgcn_mfma_f32_16x16x32_bf16(
              fah[rb][ks], fbl[cb][ks], acc[rb][cb], 0, 0, 0);
          acc[rb][cb] = __builtin_amdgcn_mfma_f32_16x16x32_bf16(
              fah[rb][ks], fbh[cb][ks], acc[rb][cb], 0, 0, 0);
        }
    __syncthreads();
  }

  // ---- epilogue (C/D layout m89: col=lane&15, row=(lane>>4)*4+reg) ----
#pragma unroll
  for (int rb = 0; rb < 2; ++rb)
#pragma unroll
    for (int cb = 0; cb < 2; ++cb)
#pragma unroll
      for (int g = 0; g < 4; ++g) {
        int gr = mt * 64 + wr * 32 + rb * 16 + g4 * 4 + g;
        int gc = nt * 64 + wc * 32 + cb * 16 + r15;
        if (MODE == 0) {
          C0[gr * N + gc] = acc[rb][cb][g];
        } else {
          int b = gr >> 8, lrow = gr & 255;
          int x = gc & 63;                       // h = nt (N=512)
          float* dst = (x < A_) ? C0 : C1;
          dst[((b * H_ + nt) * L_ + lrow) * A_ + (x & 31)] = acc[rb][cb][g];
        }
      }
}

// ---------------------------------------------------------------------------
// Attention (unchanged from round 4, validated absmax 3.9e-3):
// scores[i,j] = 0.6*(ck[i]+cq[j]) + 0.4*sum_a w_a*|k[i,a]+q[j,a]|
// masked softmax over j, PV (probs @ K) via bf16 MFMA.
// ---------------------------------------------------------------------------
__global__ __launch_bounds__(256, 2) void attn_kernel(
    const float* __restrict__ q, const float* __restrict__ k,
    const int* __restrict__ adj, const float* __restrict__ w_attn,
    float* __restrict__ vals) {
  __shared__ __align__(16) float Qt[A_][260];            // q^T fp32
  __shared__ __align__(16) __hip_bfloat16 KT[A_][264];   // k^T bf16
  __shared__ __align__(16) float Kr[ITILE][36];          // k rows fp32
  __shared__ __align__(16) __hip_bfloat16 S[ITILE][264]; // probs bf16
  __shared__ __align__(16) float wsh[A_];

  const int bh = blockIdx.x >> 3;
  const int it = blockIdx.x & 7;
  const int b = bh >> 3, h = bh & 7;
  const int t = threadIdx.x;

  const float4* qb4 = (const float4*)(q + bh * (L_ * A_));
  const float4* kb4 = (const float4*)(k + bh * (L_ * A_));
#pragma unroll
  for (int r = 0; r < 8; ++r) {
    int idx4 = r * 256 + t;
    int j = idx4 >> 3, ab = idx4 & 7;
    float4 v = qb4[idx4];
    Qt[ab * 4 + 0][j] = v.x;
    Qt[ab * 4 + 1][j] = v.y;
    Qt[ab * 4 + 2][j] = v.z;
    Qt[ab * 4 + 3][j] = v.w;
    float4 u = kb4[idx4];
    KT[ab * 4 + 0][j] = __float2bfloat16(u.x);
    KT[ab * 4 + 1][j] = __float2bfloat16(u.y);
    KT[ab * 4 + 2][j] = __float2bfloat16(u.z);
    KT[ab * 4 + 3][j] = __float2bfloat16(u.w);
  }
  {
    const float4* kr4g = (const float4*)(k + bh * (L_ * A_) + it * ITILE * A_);
    int ii = t >> 3, ab = t & 7;
    float4 v = kr4g[t];
    Kr[ii][ab * 4 + 0] = v.x;
    Kr[ii][ab * 4 + 1] = v.y;
    Kr[ii][ab * 4 + 2] = v.z;
    Kr[ii][ab * 4 + 3] = v.w;
  }
  if (t < A_) wsh[t] = w_attn[t];
  __syncthreads();

  const int wave = t >> 6, lane = t & 63;
  const int w8 = wave * 8;
  const int i0 = it * ITILE + w8;
  const int* adjb = adj + b * (L_ * L_);

  int adjv[8][4];
#pragma unroll
  for (int r = 0; r < 8; ++r)
#pragma unroll
    for (int c = 0; c < 4; ++c)
      adjv[r][c] = adjb[(i0 + r) * L_ + c * 64 + lane];

  float p[8][4] = {};
  float ck[8] = {};
  float cq[4] = {};
#pragma unroll 2
  for (int ab = 0; ab < 8; ++ab) {
    float4 wv = *(const float4*)&wsh[ab * 4];
    float4 kr4[8];
#pragma unroll
    for (int r = 0; r < 8; ++r)
      kr4[r] = *(const float4*)&Kr[w8 + r][ab * 4];
#pragma unroll
    for (int r = 0; r < 8; ++r) {
      ck[r] = fmaf(wv.x, kr4[r].x, ck[r]);
      ck[r] = fmaf(wv.y, kr4[r].y, ck[r]);
      ck[r] = fmaf(wv.z, kr4[r].z, ck[r]);
      ck[r] = fmaf(wv.w, kr4[r].w, ck[r]);
    }
#pragma unroll
    for (int c = 0; c < 4; ++c) {
      const int j = c * 64 + lane;
      float q0 = Qt[ab * 4 + 0][j];
      float q1 = Qt[ab * 4 + 1][j];
      float q2 = Qt[ab * 4 + 2][j];
      float q3 = Qt[ab * 4 + 3][j];
      cq[c] = fmaf(wv.x, q0, cq[c]);
      cq[c] = fmaf(wv.y, q1, cq[c]);
      cq[c] = fmaf(wv.z, q2, cq[c]);
      cq[c] = fmaf(wv.w, q3, cq[c]);
#pragma unroll
      for (int r = 0; r < 8; ++r) {
        p[r][c] = fmaf(wv.x, fabsf(kr4[r].x + q0), p[r][c]);
        p[r][c] = fmaf(wv.y, fabsf(kr4[r].y + q1), p[r][c]);
        p[r][c] = fmaf(wv.z, fabsf(kr4[r].z + q2), p[r][c]);
        p[r][c] = fmaf(wv.w, fabsf(kr4[r].w + q3), p[r][c]);
      }
    }
  }

#pragma unroll
  for (int r = 0; r < 8; ++r) {
    float s[4];
    float m = -3.0e38f;
#pragma unroll
    for (int c = 0; c < 4; ++c) {
      float sc = fmaf(0.4f, p[r][c], 0.6f * (ck[r] + cq[c]));
      s[c] = adjv[r][c] ? sc : -3.0e38f;
      m = fmaxf(m, s[c]);
    }
#pragma unroll
    for (int off = 32; off >= 1; off >>= 1) m = fmaxf(m, __shfl_xor(m, off));
    float sum = 0.f;
#pragma unroll
    for (int c = 0; c < 4; ++c) {
      s[c] = __expf(s[c] - m);
      sum += s[c];
    }
#pragma unroll
    for (int off = 32; off >= 1; off >>= 1) sum += __shfl_xor(sum, off);
    float inv = 1.0f / sum;
#pragma unroll
    for (int c = 0; c < 4; ++c)
      S[w8 + r][c * 64 + lane] = __float2bfloat16(s[c] * inv);
  }
  __syncthreads();

  const int mi = wave >> 1;
  const int ai = wave & 1;
  const int fr = lane & 15;
  const int fk = (lane >> 4) * 8;
  f32x4 acc = {0.f, 0.f, 0.f, 0.f};
#pragma unroll
  for (int kt = 0; kt < 8; ++kt) {
    bf16x8 afrag = *(const bf16x8*)&S[mi * 16 + fr][kt * 32 + fk];
    bf16x8 bfrag = *(const bf16x8*)&KT[ai * 16 + fr][kt * 32 + fk];
    acc = __builtin_amdgcn_mfma_f32_16x16x32_bf16(afrag, bfrag, acc, 0, 0, 0);
  }
  const int arow = ai * 16 + fr;
  const int rbase = mi * 16 + ((lane >> 4) << 2);
#pragma unroll
  for (int g = 0; g < 4; ++g) {
    int i = it * ITILE + rbase + g;
    vals[(b * L_ + i) * E_ + h * A_ + arow] = acc[g];
  }
}

extern "C" void kernel_launch(void* const* d_in, const int* in_sizes, int n_in,
                              void* d_out, int out_size, void* d_ws,
                              size_t ws_size, hipStream_t stream) {
  const float* emb = (const float*)d_in[0];
  const int* adj = (const int*)d_in[1];
  const float* W_qk = (const float*)d_in[2];
  const float* w_attn = (const float*)d_in[3];
  const float* W_out = (const float*)d_in[4];
  float* out = (float*)d_out;

  float* q = (float*)d_ws;
  float* k = q + B_ * H_ * L_ * A_;
  float* vals = k + B_ * H_ * L_ * A_;

  // qk = emb @ W_qk^T -> q,k   (M=2048, N=512)
  gemm_mfma<1><<<dim3(32 * 8), 256, 0, stream>>>(emb, W_qk, q, k, 512);
  attn_kernel<<<dim3(B_ * H_ * (L_ / ITILE)), 256, 0, stream>>>(q, k, adj,
                                                                w_attn, vals);
  // out = vals @ W_out^T      (M=2048, N=256)
  gemm_mfma<0><<<dim3(32 * 4), 256, 0, stream>>>(vals, W_out, out, nullptr,
                                                 256);
}